// Round 1
// baseline (246.646 us; speedup 1.0000x reference)
//
#include <hip/hip_runtime.h>
#include <hip/hip_bf16.h>
#include <math.h>

typedef short short8 __attribute__((ext_vector_type(8)));
typedef float f32x4 __attribute__((ext_vector_type(4)));

static constexpr int N = 8192;
static constexpr int FIN = 512;
static constexpr int FOUT = 128;
static constexpr float ALPHA = 0.2f;
static constexpr float PHI = 3.1415926f * 0.3f;
static constexpr float A_PARA = 0.5f;
static constexpr float EPS_BALL = 4e-3f;

__device__ __forceinline__ unsigned short f2b(float f) {
    union { float f; unsigned u; } v; v.f = f;
    unsigned r = v.u + 0x7fffu + ((v.u >> 16) & 1u);
    return (unsigned short)(r >> 16);
}

__device__ __forceinline__ float lrelu(float x) { return x > 0.f ? x : ALPHA * x; }

// Kernel 1: Wh = h @ W (f32 accum). Writes Wh^T as bf16 [FOUT][N], s = Wh@a1, t = Wh@a2.
__global__ __launch_bounds__(256) void k1_gemm(
    const float* __restrict__ h, const float* __restrict__ W,
    const float* __restrict__ a, unsigned short* __restrict__ whbt,
    float* __restrict__ s_out, float* __restrict__ t_out)
{
    __shared__ float hs[32][68];      // 32 rows x 64 k, +4 pad
    __shared__ float Wsh[64][128];    // 64 k x 128 cols
    const int t = threadIdx.x;
    const int i0 = blockIdx.x * 32;
    const int tx = t & 31, ty = t >> 5;   // tx: 4-col group, ty: 4-row group
    float acc[4][4] = {};
    for (int k0 = 0; k0 < FIN; k0 += 64) {
        __syncthreads();
        {   // h tile 32x64
            int r = t >> 3, c = (t & 7) * 8;
            const float* src = h + (size_t)(i0 + r) * FIN + k0 + c;
            *(float4*)&hs[r][c]     = *(const float4*)(src);
            *(float4*)&hs[r][c + 4] = *(const float4*)(src + 4);
        }
        {   // W tile 64x128
            int kk = t >> 2, c = (t & 3) * 32;
            const float* src = W + (size_t)(k0 + kk) * FOUT + c;
            #pragma unroll
            for (int u = 0; u < 8; ++u)
                *(float4*)&Wsh[kk][c + 4 * u] = *(const float4*)(src + 4 * u);
        }
        __syncthreads();
        #pragma unroll 4
        for (int kk = 0; kk < 64; ++kk) {
            float4 wv = *(const float4*)&Wsh[kk][tx * 4];
            #pragma unroll
            for (int r = 0; r < 4; ++r) {
                float hv = hs[ty * 4 + r][kk];
                acc[r][0] += hv * wv.x;
                acc[r][1] += hv * wv.y;
                acc[r][2] += hv * wv.z;
                acc[r][3] += hv * wv.w;
            }
        }
    }
    float a1[4], a2[4];
    #pragma unroll
    for (int c = 0; c < 4; ++c) { a1[c] = a[tx * 4 + c]; a2[c] = a[FOUT + tx * 4 + c]; }
    #pragma unroll
    for (int r = 0; r < 4; ++r) {
        float sp = acc[r][0]*a1[0] + acc[r][1]*a1[1] + acc[r][2]*a1[2] + acc[r][3]*a1[3];
        float tp = acc[r][0]*a2[0] + acc[r][1]*a2[1] + acc[r][2]*a2[2] + acc[r][3]*a2[3];
        #pragma unroll
        for (int m = 1; m < 32; m <<= 1) {
            sp += __shfl_xor(sp, m, 32);
            tp += __shfl_xor(tp, m, 32);
        }
        if (tx == 0) { s_out[i0 + ty*4 + r] = sp; t_out[i0 + ty*4 + r] = tp; }
        #pragma unroll
        for (int c = 0; c < 4; ++c)
            whbt[(size_t)(tx*4 + c) * N + (i0 + ty*4 + r)] = f2b(acc[r][c]);
    }
}

// Kernel 2: T = max(t)
__global__ __launch_bounds__(256) void k2_tmax(const float* __restrict__ t_in, float* __restrict__ Tout) {
    const int t = threadIdx.x;
    float m = -1e30f;
    for (int i = t; i < N; i += 256) m = fmaxf(m, t_in[i]);
    #pragma unroll
    for (int d = 1; d < 64; d <<= 1) m = fmaxf(m, __shfl_xor(m, d, 64));
    __shared__ float wm[4];
    if ((t & 63) == 0) wm[t >> 6] = m;
    __syncthreads();
    if (t == 0) Tout[0] = fmaxf(fmaxf(wm[0], wm[1]), fmaxf(wm[2], wm[3]));
}

// Kernel 3: fused masked-softmax attention + PV (bf16 MFMA) + projection/logmap/elu+cos epilogue.
// 8 waves/block: wave = (wj<<1)|wr ; wr selects 16-row half of the 32-row block tile,
// wj selects a 2048-wide j-stripe. Waves are fully independent in the main loop.
__global__ __launch_bounds__(512) void k3_attn(
    const int* __restrict__ adj, const unsigned short* __restrict__ whbt,
    const float* __restrict__ s_in, const float* __restrict__ t_in,
    const float* __restrict__ Tptr, float* __restrict__ out)
{
    __shared__ unsigned short w_lds[8][16][72];  // per-wave 16x64 bf16 w-tile (+8 pad)
    __shared__ float num_lds[2][16][128];
    __shared__ float den_lds[2][16];
    const int t = threadIdx.x;
    const int lane = t & 63, wave = t >> 6;
    const int wr = wave & 1, wj = wave >> 1;
    const int i0 = blockIdx.x * 32;

    for (int u = t; u < 2 * 16 * 128; u += 512) ((float*)num_lds)[u] = 0.f;
    if (t < 32) ((float*)den_lds)[t] = 0.f;
    __syncthreads();

    const float Tv = Tptr[0];
    const int rowA = lane >> 2;          // phase-A row (0..15)
    const int jgrp = lane & 3;           // phase-A 16-j group
    const int grow = i0 + wr * 16 + rowA;
    const float sA = s_in[grow];
    const float mA = lrelu(sA + Tv);     // fixed per-row softmax max bound
    const int* adjrow = adj + (size_t)grow * N;

    f32x4 acc[8];
    const f32x4 zz = {0.f, 0.f, 0.f, 0.f};
    #pragma unroll
    for (int c = 0; c < 8; ++c) acc[c] = zz;
    float den = 0.f;

    const int arow = lane & 15, g = lane >> 4;   // MFMA fragment coords

    for (int jt = 0; jt < 32; ++jt) {
        const int j0 = (wj * 32 + jt) * 64;
        // ---- phase A: w-tile (16 rows x 64 j) into wave-private LDS ----
        unsigned short wv[16];
        #pragma unroll
        for (int u4 = 0; u4 < 4; ++u4) {
            const int jj = jgrp * 16 + u4 * 4;
            int4  av = *(const int4*)(adjrow + j0 + jj);
            float4 tv = *(const float4*)(t_in + j0 + jj);
            float w0 = av.x > 0 ? __expf(lrelu(sA + tv.x) - mA) : 0.f;
            float w1 = av.y > 0 ? __expf(lrelu(sA + tv.y) - mA) : 0.f;
            float w2 = av.z > 0 ? __expf(lrelu(sA + tv.z) - mA) : 0.f;
            float w3 = av.w > 0 ? __expf(lrelu(sA + tv.w) - mA) : 0.f;
            den += (w0 + w1) + (w2 + w3);
            wv[u4 * 4 + 0] = f2b(w0);
            wv[u4 * 4 + 1] = f2b(w1);
            wv[u4 * 4 + 2] = f2b(w2);
            wv[u4 * 4 + 3] = f2b(w3);
        }
        short8 p0, p1;
        #pragma unroll
        for (int e = 0; e < 8; ++e) { p0[e] = (short)wv[e]; p1[e] = (short)wv[8 + e]; }
        *(short8*)&w_lds[wave][rowA][jgrp * 16]     = p0;
        *(short8*)&w_lds[wave][rowA][jgrp * 16 + 8] = p1;
        // ---- phase B: 2 MFMA k-steps of 32 (same wave; DS ops in-order) ----
        #pragma unroll
        for (int js = 0; js < 64; js += 32) {
            short8 afrag = *(const short8*)&w_lds[wave][arow][js + g * 8];
            const unsigned short* bb = whbt + (size_t)arow * N + (j0 + js + g * 8);
            #pragma unroll
            for (int c = 0; c < 8; ++c) {
                short8 bfrag = *(const short8*)(bb + (size_t)c * 16 * N);
                acc[c] = __builtin_amdgcn_mfma_f32_16x16x32_bf16(afrag, bfrag, acc[c], 0, 0, 0);
            }
        }
    }

    // ---- combine j-stripes ----
    den += __shfl_xor(den, 1, 64);
    den += __shfl_xor(den, 2, 64);
    if ((lane & 3) == 0) atomicAdd(&den_lds[wr][rowA], den);
    #pragma unroll
    for (int c = 0; c < 8; ++c) {
        #pragma unroll
        for (int q = 0; q < 4; ++q)
            atomicAdd(&num_lds[wr][g * 4 + q][c * 16 + arow], acc[c][q]);
    }
    __syncthreads();

    // ---- epilogue: normalize, project to ball, logmap0, elu + a*cos ----
    if (wj == 0) {
        #pragma unroll
        for (int q = 0; q < 4; ++q) {
            const int r16 = g * 4 + q;
            const float inv = 1.0f / den_lds[wr][r16];
            float v[8]; float ss = 0.f;
            #pragma unroll
            for (int c = 0; c < 8; ++c) {
                v[c] = num_lds[wr][r16][c * 16 + arow] * inv;
                ss += v[c] * v[c];
            }
            #pragma unroll
            for (int m = 1; m < 16; m <<= 1) ss += __shfl_xor(ss, m, 16);
            float nrm = sqrtf(ss);
            const float maxn = 1.0f - EPS_BALL;
            float scale1 = nrm > maxn ? maxn / nrm : 1.0f;
            float pn = fminf(nrm, maxn);
            float fac;
            if (pn < 1e-6f) fac = scale1;   // artanh(x)/x -> 1
            else fac = scale1 * (0.5f * __logf((1.f + pn) / (1.f - pn))) / pn;
            float* orow = out + (size_t)(i0 + wr * 16 + r16) * FOUT;
            #pragma unroll
            for (int c = 0; c < 8; ++c) {
                float hv = v[c] * fac;
                float eluv = hv > 0.f ? hv : __expf(hv) - 1.f;
                orow[c * 16 + arow] = eluv + A_PARA * __cosf(hv + PHI);
            }
        }
    }
}

extern "C" void kernel_launch(void* const* d_in, const int* in_sizes, int n_in,
                              void* d_out, int out_size, void* d_ws, size_t ws_size,
                              hipStream_t stream) {
    const float* h   = (const float*)d_in[0];
    const int*   adj = (const int*)d_in[1];
    const float* W   = (const float*)d_in[2];
    const float* a   = (const float*)d_in[3];
    float* out = (float*)d_out;

    char* ws = (char*)d_ws;
    unsigned short* whbt = (unsigned short*)ws;            // bf16 Wh^T [128][8192], 2 MB
    float* s  = (float*)(ws + (size_t)N * FOUT * 2);       // 32 KB
    float* tt = s + N;                                     // 32 KB
    float* Tp = tt + N;                                    // 4 B

    k1_gemm<<<N / 32, 256, 0, stream>>>(h, W, a, whbt, s, tt);
    k2_tmax<<<1, 256, 0, stream>>>(tt, Tp);
    k3_attn<<<N / 32, 512, 0, stream>>>(adj, whbt, s, tt, Tp, out);
}

// Round 2
// 244.304 us; speedup vs baseline: 1.0096x; 1.0096x over previous
//
#include <hip/hip_runtime.h>
#include <hip/hip_bf16.h>
#include <math.h>

typedef short short8 __attribute__((ext_vector_type(8)));
typedef float f32x4 __attribute__((ext_vector_type(4)));

static constexpr int N = 8192;
static constexpr int FIN = 512;
static constexpr int FOUT = 128;
static constexpr float ALPHA = 0.2f;
static constexpr float PHI = 3.1415926f * 0.3f;
static constexpr float A_PARA = 0.5f;
static constexpr float EPS_BALL = 4e-3f;

__device__ __forceinline__ unsigned short f2b(float f) {
    union { float f; unsigned u; } v; v.f = f;
    unsigned r = v.u + 0x7fffu + ((v.u >> 16) & 1u);
    return (unsigned short)(r >> 16);
}

__device__ __forceinline__ float lrelu(float x) { return x > 0.f ? x : ALPHA * x; }

// Kernel 1: Wh = h @ W (f32 accum). Writes Wh^T as bf16 [FOUT][N], s = Wh@a1, t = Wh@a2.
__global__ __launch_bounds__(256) void k1_gemm(
    const float* __restrict__ h, const float* __restrict__ W,
    const float* __restrict__ a, unsigned short* __restrict__ whbt,
    float* __restrict__ s_out, float* __restrict__ t_out)
{
    __shared__ float hs[32][68];      // 32 rows x 64 k, +4 pad
    __shared__ float Wsh[64][128];    // 64 k x 128 cols
    const int t = threadIdx.x;
    const int i0 = blockIdx.x * 32;
    const int tx = t & 31, ty = t >> 5;   // tx: 4-col group, ty: 4-row group
    float acc[4][4] = {};
    for (int k0 = 0; k0 < FIN; k0 += 64) {
        __syncthreads();
        {   // h tile 32x64
            int r = t >> 3, c = (t & 7) * 8;
            const float* src = h + (size_t)(i0 + r) * FIN + k0 + c;
            *(float4*)&hs[r][c]     = *(const float4*)(src);
            *(float4*)&hs[r][c + 4] = *(const float4*)(src + 4);
        }
        {   // W tile 64x128
            int kk = t >> 2, c = (t & 3) * 32;
            const float* src = W + (size_t)(k0 + kk) * FOUT + c;
            #pragma unroll
            for (int u = 0; u < 8; ++u)
                *(float4*)&Wsh[kk][c + 4 * u] = *(const float4*)(src + 4 * u);
        }
        __syncthreads();
        #pragma unroll 4
        for (int kk = 0; kk < 64; ++kk) {
            float4 wv = *(const float4*)&Wsh[kk][tx * 4];
            #pragma unroll
            for (int r = 0; r < 4; ++r) {
                float hv = hs[ty * 4 + r][kk];
                acc[r][0] += hv * wv.x;
                acc[r][1] += hv * wv.y;
                acc[r][2] += hv * wv.z;
                acc[r][3] += hv * wv.w;
            }
        }
    }
    float a1[4], a2[4];
    #pragma unroll
    for (int c = 0; c < 4; ++c) { a1[c] = a[tx * 4 + c]; a2[c] = a[FOUT + tx * 4 + c]; }
    #pragma unroll
    for (int r = 0; r < 4; ++r) {
        float sp = acc[r][0]*a1[0] + acc[r][1]*a1[1] + acc[r][2]*a1[2] + acc[r][3]*a1[3];
        float tp = acc[r][0]*a2[0] + acc[r][1]*a2[1] + acc[r][2]*a2[2] + acc[r][3]*a2[3];
        #pragma unroll
        for (int m = 1; m < 32; m <<= 1) {
            sp += __shfl_xor(sp, m, 32);
            tp += __shfl_xor(tp, m, 32);
        }
        if (tx == 0) { s_out[i0 + ty*4 + r] = sp; t_out[i0 + ty*4 + r] = tp; }
        #pragma unroll
        for (int c = 0; c < 4; ++c)
            whbt[(size_t)(tx*4 + c) * N + (i0 + ty*4 + r)] = f2b(acc[r][c]);
    }
}

// Kernel 2: T = max(t)
__global__ __launch_bounds__(256) void k2_tmax(const float* __restrict__ t_in, float* __restrict__ Tout) {
    const int t = threadIdx.x;
    float m = -1e30f;
    for (int i = t; i < N; i += 256) m = fmaxf(m, t_in[i]);
    #pragma unroll
    for (int d = 1; d < 64; d <<= 1) m = fmaxf(m, __shfl_xor(m, d, 64));
    __shared__ float wm[4];
    if ((t & 63) == 0) wm[t >> 6] = m;
    __syncthreads();
    if (t == 0) Tout[0] = fmaxf(fmaxf(wm[0], wm[1]), fmaxf(wm[2], wm[3]));
}

// Kernel 3: fused masked-softmax attention + PV (bf16 MFMA) + projection/logmap/elu+cos.
// 512 blocks x 512 threads. Each block owns 16 rows; wave wj (0..7) owns a
// 1024-wide j-stripe (16 iters of 64). 2 blocks/CU -> 16 waves/CU (50% occ).
// adj loads are software-pipelined one jt ahead (HBM latency hides under
// exp+MFMA of the current iteration). Waves independent in the main loop;
// combine via LDS atomics at the end.
__global__ __launch_bounds__(512, 4) void k3_attn(
    const int* __restrict__ adj, const unsigned short* __restrict__ whbt,
    const float* __restrict__ s_in, const float* __restrict__ t_in,
    const float* __restrict__ Tptr, float* __restrict__ out)
{
    __shared__ unsigned short w_lds[8][16][72];  // per-wave 16x64 bf16 w-tile (+8 pad)
    __shared__ float num_lds[16][128];
    __shared__ float den_lds[16];
    const int t = threadIdx.x;
    const int lane = t & 63, wave = t >> 6;      // wave == wj (j-stripe index)
    const int i0 = blockIdx.x * 16;

    for (int u = t; u < 16 * 128; u += 512) ((float*)num_lds)[u] = 0.f;
    if (t < 16) den_lds[t] = 0.f;
    __syncthreads();

    const float Tv = Tptr[0];
    const int rowA = lane >> 2;          // phase-A row (0..15)
    const int jgrp = lane & 3;           // phase-A 16-j group
    const int grow = i0 + rowA;
    const float sA = s_in[grow];
    const float mA = lrelu(sA + Tv);     // fixed per-row softmax max bound
    const int* adjrow = adj + (size_t)grow * N;

    f32x4 acc[8];
    const f32x4 zz = {0.f, 0.f, 0.f, 0.f};
    #pragma unroll
    for (int c = 0; c < 8; ++c) acc[c] = zz;
    float den = 0.f;

    const int arow = lane & 15, g = lane >> 4;   // MFMA fragment coords
    const int jbase = wave * 1024;

    // prologue: prefetch adj for jt=0
    int4 av[4];
    #pragma unroll
    for (int u4 = 0; u4 < 4; ++u4)
        av[u4] = *(const int4*)(adjrow + jbase + jgrp * 16 + u4 * 4);

    #pragma unroll 1
    for (int jt = 0; jt < 16; ++jt) {
        const int j0 = jbase + jt * 64;
        // ---- prefetch next iteration's adj (HBM latency hides under this iter) ----
        int4 avn[4];
        if (jt < 15) {
            #pragma unroll
            for (int u4 = 0; u4 < 4; ++u4)
                avn[u4] = *(const int4*)(adjrow + j0 + 64 + jgrp * 16 + u4 * 4);
        }
        // ---- phase A: w-tile (16 rows x 64 j) into wave-private LDS ----
        unsigned short wv[16];
        float denl = 0.f;
        #pragma unroll
        for (int u4 = 0; u4 < 4; ++u4) {
            const int jj = j0 + jgrp * 16 + u4 * 4;
            float4 tv = *(const float4*)(t_in + jj);
            float w0 = av[u4].x > 0 ? __expf(lrelu(sA + tv.x) - mA) : 0.f;
            float w1 = av[u4].y > 0 ? __expf(lrelu(sA + tv.y) - mA) : 0.f;
            float w2 = av[u4].z > 0 ? __expf(lrelu(sA + tv.z) - mA) : 0.f;
            float w3 = av[u4].w > 0 ? __expf(lrelu(sA + tv.w) - mA) : 0.f;
            denl += (w0 + w1) + (w2 + w3);
            wv[u4 * 4 + 0] = f2b(w0);
            wv[u4 * 4 + 1] = f2b(w1);
            wv[u4 * 4 + 2] = f2b(w2);
            wv[u4 * 4 + 3] = f2b(w3);
        }
        den += denl;
        short8 p0, p1;
        #pragma unroll
        for (int e = 0; e < 8; ++e) { p0[e] = (short)wv[e]; p1[e] = (short)wv[8 + e]; }
        *(short8*)&w_lds[wave][rowA][jgrp * 16]     = p0;
        *(short8*)&w_lds[wave][rowA][jgrp * 16 + 8] = p1;
        // ---- phase B: 2 MFMA k-steps of 32 (same wave; DS ops in-order) ----
        #pragma unroll
        for (int js = 0; js < 64; js += 32) {
            short8 afrag = *(const short8*)&w_lds[wave][arow][js + g * 8];
            const unsigned short* bb = whbt + (size_t)arow * N + (j0 + js + g * 8);
            #pragma unroll
            for (int c = 0; c < 8; ++c) {
                short8 bfrag = *(const short8*)(bb + (size_t)c * 16 * N);
                acc[c] = __builtin_amdgcn_mfma_f32_16x16x32_bf16(afrag, bfrag, acc[c], 0, 0, 0);
            }
        }
        // ---- shift prefetch regs ----
        #pragma unroll
        for (int u4 = 0; u4 < 4; ++u4) av[u4] = avn[u4];
    }

    // ---- combine j-stripes ----
    den += __shfl_xor(den, 1, 64);
    den += __shfl_xor(den, 2, 64);
    if ((lane & 3) == 0) atomicAdd(&den_lds[rowA], den);
    #pragma unroll
    for (int c = 0; c < 8; ++c) {
        #pragma unroll
        for (int q = 0; q < 4; ++q)
            atomicAdd(&num_lds[g * 4 + q][c * 16 + arow], acc[c][q]);
    }
    __syncthreads();

    // ---- epilogue: normalize, project to ball, logmap0, elu + a*cos ----
    if (wave == 0) {
        #pragma unroll
        for (int q = 0; q < 4; ++q) {
            const int r16 = g * 4 + q;
            const float inv = 1.0f / den_lds[r16];
            float v[8]; float ss = 0.f;
            #pragma unroll
            for (int c = 0; c < 8; ++c) {
                v[c] = num_lds[r16][c * 16 + arow] * inv;
                ss += v[c] * v[c];
            }
            #pragma unroll
            for (int m = 1; m < 16; m <<= 1) ss += __shfl_xor(ss, m, 16);
            float nrm = sqrtf(ss);
            const float maxn = 1.0f - EPS_BALL;
            float scale1 = nrm > maxn ? maxn / nrm : 1.0f;
            float pn = fminf(nrm, maxn);
            float fac;
            if (pn < 1e-6f) fac = scale1;   // artanh(x)/x -> 1
            else fac = scale1 * (0.5f * __logf((1.f + pn) / (1.f - pn))) / pn;
            float* orow = out + (size_t)(i0 + r16) * FOUT;
            #pragma unroll
            for (int c = 0; c < 8; ++c) {
                float hv = v[c] * fac;
                float eluv = hv > 0.f ? hv : __expf(hv) - 1.f;
                orow[c * 16 + arow] = eluv + A_PARA * __cosf(hv + PHI);
            }
        }
    }
}

extern "C" void kernel_launch(void* const* d_in, const int* in_sizes, int n_in,
                              void* d_out, int out_size, void* d_ws, size_t ws_size,
                              hipStream_t stream) {
    const float* h   = (const float*)d_in[0];
    const int*   adj = (const int*)d_in[1];
    const float* W   = (const float*)d_in[2];
    const float* a   = (const float*)d_in[3];
    float* out = (float*)d_out;

    char* ws = (char*)d_ws;
    unsigned short* whbt = (unsigned short*)ws;            // bf16 Wh^T [128][8192], 2 MB
    float* s  = (float*)(ws + (size_t)N * FOUT * 2);       // 32 KB
    float* tt = s + N;                                     // 32 KB
    float* Tp = tt + N;                                    // 4 B

    k1_gemm<<<N / 32, 256, 0, stream>>>(h, W, a, whbt, s, tt);
    k2_tmax<<<1, 256, 0, stream>>>(tt, Tp);
    k3_attn<<<N / 16, 512, 0, stream>>>(adj, whbt, s, tt, Tp, out);
}

// Round 3
// 150.871 us; speedup vs baseline: 1.6348x; 1.6193x over previous
//
#include <hip/hip_runtime.h>
#include <hip/hip_bf16.h>
#include <math.h>

typedef short short8 __attribute__((ext_vector_type(8)));
typedef float f32x4 __attribute__((ext_vector_type(4)));

static constexpr int N = 8192;
static constexpr int FIN = 512;
static constexpr int FOUT = 128;
static constexpr float ALPHA = 0.2f;
static constexpr float PHI = 3.1415926f * 0.3f;
static constexpr float A_PARA = 0.5f;
static constexpr float EPS_BALL = 4e-3f;

__device__ __forceinline__ unsigned short f2b(float f) {
    union { float f; unsigned u; } v; v.f = f;
    unsigned r = v.u + 0x7fffu + ((v.u >> 16) & 1u);
    return (unsigned short)(r >> 16);
}

__device__ __forceinline__ float lrelu(float x) { return x > 0.f ? x : ALPHA * x; }

// monotone f32 -> u32 key for atomicMax-based float max
__device__ __forceinline__ unsigned f2key(float x) {
    unsigned b = __float_as_uint(x);
    return (b & 0x80000000u) ? ~b : (b | 0x80000000u);
}
__device__ __forceinline__ float key2f(unsigned k) {
    unsigned b = (k & 0x80000000u) ? (k ^ 0x80000000u) : ~k;
    return __uint_as_float(b);
}

// Kernel 1: Wh = h @ W (f32 accum). Writes Wh^T as bf16 [FOUT][N], s = Wh@a1, t = Wh@a2,
// and global max(t) via key-transformed atomicMax (replaces old k2).
__global__ __launch_bounds__(256) void k1_gemm(
    const float* __restrict__ h, const float* __restrict__ W,
    const float* __restrict__ a, unsigned short* __restrict__ whbt,
    float* __restrict__ s_out, float* __restrict__ t_out,
    unsigned* __restrict__ Tkey)
{
    __shared__ float hs[32][68];      // 32 rows x 64 k, +4 pad
    __shared__ float Wsh[64][128];    // 64 k x 128 cols
    const int t = threadIdx.x;
    const int i0 = blockIdx.x * 32;
    const int tx = t & 31, ty = t >> 5;   // tx: 4-col group, ty: 4-row group
    float acc[4][4] = {};
    for (int k0 = 0; k0 < FIN; k0 += 64) {
        __syncthreads();
        {   // h tile 32x64
            int r = t >> 3, c = (t & 7) * 8;
            const float* src = h + (size_t)(i0 + r) * FIN + k0 + c;
            *(float4*)&hs[r][c]     = *(const float4*)(src);
            *(float4*)&hs[r][c + 4] = *(const float4*)(src + 4);
        }
        {   // W tile 64x128
            int kk = t >> 2, c = (t & 3) * 32;
            const float* src = W + (size_t)(k0 + kk) * FOUT + c;
            #pragma unroll
            for (int u = 0; u < 8; ++u)
                *(float4*)&Wsh[kk][c + 4 * u] = *(const float4*)(src + 4 * u);
        }
        __syncthreads();
        #pragma unroll 4
        for (int kk = 0; kk < 64; ++kk) {
            float4 wv = *(const float4*)&Wsh[kk][tx * 4];
            #pragma unroll
            for (int r = 0; r < 4; ++r) {
                float hv = hs[ty * 4 + r][kk];
                acc[r][0] += hv * wv.x;
                acc[r][1] += hv * wv.y;
                acc[r][2] += hv * wv.z;
                acc[r][3] += hv * wv.w;
            }
        }
    }
    float a1[4], a2[4];
    #pragma unroll
    for (int c = 0; c < 4; ++c) { a1[c] = a[tx * 4 + c]; a2[c] = a[FOUT + tx * 4 + c]; }
    float tmax = -1e30f;
    #pragma unroll
    for (int r = 0; r < 4; ++r) {
        float sp = acc[r][0]*a1[0] + acc[r][1]*a1[1] + acc[r][2]*a1[2] + acc[r][3]*a1[3];
        float tp = acc[r][0]*a2[0] + acc[r][1]*a2[1] + acc[r][2]*a2[2] + acc[r][3]*a2[3];
        #pragma unroll
        for (int m = 1; m < 32; m <<= 1) {
            sp += __shfl_xor(sp, m, 32);
            tp += __shfl_xor(tp, m, 32);
        }
        if (tx == 0) { s_out[i0 + ty*4 + r] = sp; t_out[i0 + ty*4 + r] = tp; }
        tmax = fmaxf(tmax, tp);
        #pragma unroll
        for (int c = 0; c < 4; ++c)
            whbt[(size_t)(tx*4 + c) * N + (i0 + ty*4 + r)] = f2b(acc[r][c]);
    }
    if (tx == 0) atomicMax(Tkey, f2key(tmax));
}

// Kernel 3: fused masked-softmax attention + PV (bf16 MFMA).
// Grid 512 = 64 i-tiles (BM=128 rows) x 8 j-chunks (BJ=1024). jc = blockIdx%8 so
// each XCD hosts one j-chunk -> its 256 KB whbt slice stays L2-resident.
// Per block: whbt tile [128 FOUT][64 j] double-buffered in LDS, shared by all
// 8 waves (wave w owns rows w*16..w*16+15). One barrier per jt iteration.
// MFMA operands both come from LDS (lgkmcnt only); adj + next whbt tile are
// prefetched into registers and drained only at the post-compute ds_write.
// Cross-block (j-chunk) combine: partial num slices in ws (fast) or
// atomicAdd into out (fallback), reduced by k4.
__global__ __launch_bounds__(512, 4) void k3_attn(
    const int* __restrict__ adj, const unsigned short* __restrict__ whbt,
    const float* __restrict__ s_in, const float* __restrict__ t_in,
    const unsigned* __restrict__ Tkey, float* __restrict__ num_out,
    float* __restrict__ den_out, int slice_mode)
{
    __shared__ unsigned short bt_lds[2][128][72];   // whbt tile dbuf, pad 64->72 (2-way max)
    __shared__ unsigned short w_lds[8][16][72];     // per-wave w-tile
    const int t = threadIdx.x;
    const int lane = t & 63, wave = t >> 6;
    const int jc = blockIdx.x & 7, it = blockIdx.x >> 3;
    const int i0 = it * 128;
    const int jbase = jc * 1024;

    const float Tv = key2f(Tkey[0]);
    const int rowA = lane >> 2, jgrp = lane & 3;
    const int grow = i0 + wave * 16 + rowA;
    const float sA = s_in[grow];
    const float mA = lrelu(sA + Tv);     // fixed per-row softmax max bound
    const int* adjrow = adj + (size_t)grow * N;
    const int arow = lane & 15, g = lane >> 4;   // MFMA fragment coords

    // whbt staging coords: thread loads 32B of row srow at col scol
    const int srow = t >> 2;
    const int scol = (t & 3) * 16;
    const unsigned short* sbase = whbt + (size_t)srow * N + jbase + scol;

    f32x4 acc[8];
    const f32x4 zz = {0.f, 0.f, 0.f, 0.f};
    #pragma unroll
    for (int c = 0; c < 8; ++c) acc[c] = zz;
    float den = 0.f;

    // ---- prologue: stage tile 0, prefetch adj for jt=0 ----
    short8 sr0 = *(const short8*)(sbase);
    short8 sr1 = *(const short8*)(sbase + 8);
    int4 av[4];
    #pragma unroll
    for (int u4 = 0; u4 < 4; ++u4)
        av[u4] = *(const int4*)(adjrow + jbase + jgrp * 16 + u4 * 4);
    *(short8*)&bt_lds[0][srow][scol]     = sr0;
    *(short8*)&bt_lds[0][srow][scol + 8] = sr1;
    __syncthreads();

    #pragma unroll 1
    for (int jt = 0; jt < 16; ++jt) {
        const int cur = jt & 1;
        const int j0 = jbase + jt * 64;
        // t_in loads FIRST so their wait doesn't drain the prefetches (vmcnt order)
        float4 tvv[4];
        #pragma unroll
        for (int u4 = 0; u4 < 4; ++u4)
            tvv[u4] = *(const float4*)(t_in + j0 + jgrp * 16 + u4 * 4);
        // prefetch next adj + next whbt tile into regs (drained after compute)
        int4 avn[4]; short8 n0, n1;
        if (jt < 15) {
            #pragma unroll
            for (int u4 = 0; u4 < 4; ++u4)
                avn[u4] = *(const int4*)(adjrow + j0 + 64 + jgrp * 16 + u4 * 4);
            const unsigned short* p = sbase + (jt + 1) * 64;
            n0 = *(const short8*)p;
            n1 = *(const short8*)(p + 8);
        }
        // ---- phase A: w-tile (16 rows x 64 j) into wave-private LDS ----
        unsigned short wv[16];
        float denl = 0.f;
        #pragma unroll
        for (int u4 = 0; u4 < 4; ++u4) {
            float4 tv = tvv[u4];
            float w0 = av[u4].x > 0 ? __expf(lrelu(sA + tv.x) - mA) : 0.f;
            float w1 = av[u4].y > 0 ? __expf(lrelu(sA + tv.y) - mA) : 0.f;
            float w2 = av[u4].z > 0 ? __expf(lrelu(sA + tv.z) - mA) : 0.f;
            float w3 = av[u4].w > 0 ? __expf(lrelu(sA + tv.w) - mA) : 0.f;
            denl += (w0 + w1) + (w2 + w3);
            wv[u4 * 4 + 0] = f2b(w0);
            wv[u4 * 4 + 1] = f2b(w1);
            wv[u4 * 4 + 2] = f2b(w2);
            wv[u4 * 4 + 3] = f2b(w3);
        }
        den += denl;
        short8 p0, p1;
        #pragma unroll
        for (int e = 0; e < 8; ++e) { p0[e] = (short)wv[e]; p1[e] = (short)wv[8 + e]; }
        *(short8*)&w_lds[wave][rowA][jgrp * 16]     = p0;
        *(short8*)&w_lds[wave][rowA][jgrp * 16 + 8] = p1;
        // ---- phase B: 16 MFMA, both operands from LDS ----
        #pragma unroll
        for (int js = 0; js < 64; js += 32) {
            short8 afrag = *(const short8*)&w_lds[wave][arow][js + g * 8];
            #pragma unroll
            for (int c = 0; c < 8; ++c) {
                short8 bfrag = *(const short8*)&bt_lds[cur][c * 16 + arow][js + g * 8];
                acc[c] = __builtin_amdgcn_mfma_f32_16x16x32_bf16(afrag, bfrag, acc[c], 0, 0, 0);
            }
        }
        // ---- stage next tile (vmcnt drain happens here, after compute) ----
        if (jt < 15) {
            *(short8*)&bt_lds[cur ^ 1][srow][scol]     = n0;
            *(short8*)&bt_lds[cur ^ 1][srow][scol + 8] = n1;
            #pragma unroll
            for (int u4 = 0; u4 < 4; ++u4) av[u4] = avn[u4];
            __syncthreads();
        }
    }

    // ---- den: reduce over jgrp lanes, one global atomic per row ----
    float d = den;
    d += __shfl_xor(d, 1, 64);
    d += __shfl_xor(d, 2, 64);
    if (jgrp == 0) atomicAdd(&den_out[grow], d);

    // ---- num: partial write (slice per jc) or atomic fallback ----
    const int orow0 = i0 + wave * 16;
    if (slice_mode) {
        float* dst = num_out + (size_t)jc * ((size_t)N * FOUT);
        #pragma unroll
        for (int c = 0; c < 8; ++c)
            #pragma unroll
            for (int q = 0; q < 4; ++q)
                dst[(size_t)(orow0 + g * 4 + q) * FOUT + c * 16 + arow] = acc[c][q];
    } else {
        #pragma unroll
        for (int c = 0; c < 8; ++c)
            #pragma unroll
            for (int q = 0; q < 4; ++q)
                atomicAdd(&num_out[(size_t)(orow0 + g * 4 + q) * FOUT + c * 16 + arow], acc[c][q]);
    }
}

// Kernel 4: reduce j-chunk partials, normalize, project, logmap0, elu + a*cos.
// nsl=8 (slices in ws) or nsl=1 (num accumulated in out via atomics; in-place).
__global__ __launch_bounds__(256) void k4_epi(
    const float* __restrict__ num, const float* __restrict__ den,
    float* __restrict__ out, int nsl)
{
    const int row = blockIdx.x * 16 + (threadIdx.x >> 4);
    const int l = threadIdx.x & 15;
    const float inv = 1.0f / den[row];
    float v[8]; float ss = 0.f;
    #pragma unroll
    for (int c = 0; c < 8; ++c) {
        float x = 0.f;
        for (int s5 = 0; s5 < nsl; ++s5)
            x += num[(size_t)s5 * N * FOUT + (size_t)row * FOUT + c * 16 + l];
        v[c] = x * inv;
        ss += v[c] * v[c];
    }
    #pragma unroll
    for (int m = 1; m < 16; m <<= 1) ss += __shfl_xor(ss, m, 16);
    float nrm = sqrtf(ss);
    const float maxn = 1.0f - EPS_BALL;
    float scale1 = nrm > maxn ? maxn / nrm : 1.0f;
    float pn = fminf(nrm, maxn);
    float fac;
    if (pn < 1e-6f) fac = scale1;   // artanh(x)/x -> 1
    else fac = scale1 * (0.5f * __logf((1.f + pn) / (1.f - pn))) / pn;
    #pragma unroll
    for (int c = 0; c < 8; ++c) {
        float hv = v[c] * fac;
        float eluv = hv > 0.f ? hv : __expf(hv) - 1.f;
        out[(size_t)row * FOUT + c * 16 + l] = eluv + A_PARA * __cosf(hv + PHI);
    }
}

extern "C" void kernel_launch(void* const* d_in, const int* in_sizes, int n_in,
                              void* d_out, int out_size, void* d_ws, size_t ws_size,
                              hipStream_t stream) {
    const float* h   = (const float*)d_in[0];
    const int*   adj = (const int*)d_in[1];
    const float* W   = (const float*)d_in[2];
    const float* a   = (const float*)d_in[3];
    float* out = (float*)d_out;

    char* ws = (char*)d_ws;
    unsigned short* whbt = (unsigned short*)ws;                 // bf16 Wh^T [128][8192], 2 MB
    size_t off = (size_t)N * FOUT * 2;
    float* s  = (float*)(ws + off); off += (size_t)N * 4;
    float* tt = (float*)(ws + off); off += (size_t)N * 4;
    unsigned* Tkey = (unsigned*)(ws + off); off += 256;
    float* denb = (float*)(ws + off); off += (size_t)N * 4;
    const size_t slice_bytes = (size_t)N * FOUT * 4;            // 4 MB per j-chunk
    const bool fast = ws_size >= off + 8 * slice_bytes;
    float* numdst = fast ? (float*)(ws + off) : out;

    hipMemsetAsync(Tkey, 0, 4, stream);
    hipMemsetAsync(denb, 0, (size_t)N * 4, stream);
    if (!fast) hipMemsetAsync(out, 0, slice_bytes, stream);

    k1_gemm<<<N / 32, 256, 0, stream>>>(h, W, a, whbt, s, tt, Tkey);
    k3_attn<<<512, 512, 0, stream>>>(adj, whbt, s, tt, Tkey, numdst, denb, fast ? 1 : 0);
    k4_epi<<<N / 16, 256, 0, stream>>>(numdst, denb, out, fast ? 8 : 1);
}

// Round 4
// 104.380 us; speedup vs baseline: 2.3630x; 1.4454x over previous
//
#include <hip/hip_runtime.h>
#include <hip/hip_bf16.h>
#include <math.h>

typedef short short8 __attribute__((ext_vector_type(8)));
typedef float f32x4 __attribute__((ext_vector_type(4)));

static constexpr int N = 8192;
static constexpr int FIN = 512;
static constexpr int FOUT = 128;
static constexpr float PHI = 3.1415926f * 0.3f;
static constexpr float A_PARA = 0.5f;
static constexpr float EPS_BALL = 4e-3f;
static constexpr float L2E = 1.4426950408889634f;   // log2(e)

__device__ __forceinline__ unsigned short f2b(float f) {
    union { float f; unsigned u; } v; v.f = f;
    unsigned r = v.u + 0x7fffu + ((v.u >> 16) & 1u);
    return (unsigned short)(r >> 16);
}

// monotone f32 -> u32 key for atomicMax-based float max
__device__ __forceinline__ unsigned f2key(float x) {
    unsigned b = __float_as_uint(x);
    return (b & 0x80000000u) ? ~b : (b | 0x80000000u);
}
__device__ __forceinline__ float key2f(unsigned k) {
    unsigned b = (k & 0x80000000u) ? (k ^ 0x80000000u) : ~k;
    return __uint_as_float(b);
}

__device__ __forceinline__ short8 cvt8(float4 x0, float4 x1) {
    short8 r;
    r[0] = (short)f2b(x0.x); r[1] = (short)f2b(x0.y);
    r[2] = (short)f2b(x0.z); r[3] = (short)f2b(x0.w);
    r[4] = (short)f2b(x1.x); r[5] = (short)f2b(x1.y);
    r[6] = (short)f2b(x1.z); r[7] = (short)f2b(x1.w);
    return r;
}

// w = exp2( lrelu(s'+t') - m' ) masked by adj; everything pre-scaled by log2e.
__device__ __forceinline__ void cw(float* w, const int4 a, const float4 tv,
                                   float sA, float mA) {
    float z;
    z = sA + tv.x; w[0] = a.x > 0 ? __builtin_amdgcn_exp2f(fmaxf(z, 0.2f * z) - mA) : 0.f;
    z = sA + tv.y; w[1] = a.y > 0 ? __builtin_amdgcn_exp2f(fmaxf(z, 0.2f * z) - mA) : 0.f;
    z = sA + tv.z; w[2] = a.z > 0 ? __builtin_amdgcn_exp2f(fmaxf(z, 0.2f * z) - mA) : 0.f;
    z = sA + tv.w; w[3] = a.w > 0 ? __builtin_amdgcn_exp2f(fmaxf(z, 0.2f * z) - mA) : 0.f;
}

// Kernel 0: W f32[512][128] -> Wt bf16[128][512] (transposed for k1 B-fragments)
__global__ __launch_bounds__(256) void k0_wt(const float* __restrict__ W,
                                             unsigned short* __restrict__ Wt) {
    __shared__ float sh[32][33];
    const int t = threadIdx.x;
    const int k0 = (blockIdx.x >> 2) * 32, c0 = (blockIdx.x & 3) * 32;
    {
        int r = t >> 3, c4 = (t & 7) * 4;
        float4 v = *(const float4*)(W + (size_t)(k0 + r) * FOUT + c0 + c4);
        sh[r][c4] = v.x; sh[r][c4 + 1] = v.y; sh[r][c4 + 2] = v.z; sh[r][c4 + 3] = v.w;
    }
    __syncthreads();
    int cc = t >> 3, k4 = (t & 7) * 4;
    ushort4 o;
    o.x = f2b(sh[k4][cc]); o.y = f2b(sh[k4 + 1][cc]);
    o.z = f2b(sh[k4 + 2][cc]); o.w = f2b(sh[k4 + 3][cc]);
    *(ushort4*)(Wt + (size_t)(c0 + cc) * FIN + k0 + k4) = o;
}

// Kernel 1: Wh = h @ W via bf16 MFMA (f32 accum). Outputs whbt bf16 [FOUT][N],
// s' = (Wh@a1)*log2e, t' = (Wh@a2)*log2e, Tkey = max key of t'.
// 256 blocks x 256 thr (4 waves: wr=wave&1 row-half, wc=wave>>1 col-half).
__global__ __launch_bounds__(256) void k1_gemm(
    const float* __restrict__ h, const unsigned short* __restrict__ Wt,
    const float* __restrict__ a, unsigned short* __restrict__ whbt,
    float* __restrict__ s_out, float* __restrict__ t_out,
    unsigned* __restrict__ Tkey)
{
    __shared__ unsigned short hsb[2][32][72];
    __shared__ float sred[32][2], tred[32][2];
    const int t = threadIdx.x, lane = t & 63, wave = t >> 6;
    const int i0 = blockIdx.x * 32;
    const int wr = wave & 1, wc = wave >> 1;
    const int arow = lane & 15, g = lane >> 4;
    const int sr = t >> 3, sc = (t & 7) * 8;
    const float* hp = h + (size_t)(i0 + sr) * FIN + sc;

    float4 x0 = *(const float4*)hp, x1 = *(const float4*)(hp + 4);
    *(short8*)&hsb[0][sr][sc] = cvt8(x0, x1);
    __syncthreads();

    f32x4 acc[4];
    const f32x4 zz = {0.f, 0.f, 0.f, 0.f};
    #pragma unroll
    for (int cf = 0; cf < 4; ++cf) acc[cf] = zz;

    #pragma unroll 1
    for (int kt = 0; kt < 8; ++kt) {
        const int cur = kt & 1;
        float4 y0, y1;
        if (kt < 7) {
            y0 = *(const float4*)(hp + (kt + 1) * 64);
            y1 = *(const float4*)(hp + (kt + 1) * 64 + 4);
        }
        #pragma unroll
        for (int js = 0; js < 64; js += 32) {
            short8 af = *(const short8*)&hsb[cur][wr * 16 + arow][js + g * 8];
            #pragma unroll
            for (int cf = 0; cf < 4; ++cf) {
                const unsigned short* bp =
                    Wt + (size_t)(wc * 64 + cf * 16 + arow) * FIN + kt * 64 + js + g * 8;
                short8 bf = *(const short8*)bp;
                acc[cf] = __builtin_amdgcn_mfma_f32_16x16x32_bf16(af, bf, acc[cf], 0, 0, 0);
            }
        }
        if (kt < 7) {
            *(short8*)&hsb[cur ^ 1][sr][sc] = cvt8(y0, y1);
            __syncthreads();
        }
    }

    float a1v[4], a2v[4];
    #pragma unroll
    for (int cf = 0; cf < 4; ++cf) {
        int col = wc * 64 + cf * 16 + arow;
        a1v[cf] = a[col]; a2v[cf] = a[FOUT + col];
    }
    // whbt store: 4 contiguous rows per (thread,cf)
    #pragma unroll
    for (int cf = 0; cf < 4; ++cf) {
        int col = wc * 64 + cf * 16 + arow;
        ushort4 o;
        o.x = f2b(acc[cf][0]); o.y = f2b(acc[cf][1]);
        o.z = f2b(acc[cf][2]); o.w = f2b(acc[cf][3]);
        *(ushort4*)(whbt + (size_t)col * N + i0 + wr * 16 + g * 4) = o;
    }
    // s,t partials -> lane-reduce over cols (arow) -> LDS -> combine wc halves
    #pragma unroll
    for (int q = 0; q < 4; ++q) {
        float sp = acc[0][q]*a1v[0] + acc[1][q]*a1v[1] + acc[2][q]*a1v[2] + acc[3][q]*a1v[3];
        float tp = acc[0][q]*a2v[0] + acc[1][q]*a2v[1] + acc[2][q]*a2v[2] + acc[3][q]*a2v[3];
        #pragma unroll
        for (int m = 1; m < 16; m <<= 1) {
            sp += __shfl_xor(sp, m, 16);
            tp += __shfl_xor(tp, m, 16);
        }
        if (arow == 0) {
            sred[wr * 16 + g * 4 + q][wc] = sp;
            tred[wr * 16 + g * 4 + q][wc] = tp;
        }
    }
    __syncthreads();
    if (t < 32) {
        float sp = (sred[t][0] + sred[t][1]) * L2E;
        float tp = (tred[t][0] + tred[t][1]) * L2E;
        s_out[i0 + t] = sp;
        t_out[i0 + t] = tp;
        float m = tp;
        #pragma unroll
        for (int d = 1; d < 32; d <<= 1) m = fmaxf(m, __shfl_xor(m, d, 32));
        if (t == 0) atomicMax(Tkey, f2key(m));
    }
}

// Kernel 3: fused masked-softmax attention + PV (bf16 MFMA).
// Grid 512 = 64 i-tiles (BM=128) x 8 j-chunks (BJ=1024), jc = blockIdx%8 (XCD-pinned).
// Phase A computes w directly in MFMA A-fragment layout (lane(arow,g) owns
// w[arow][js+g*8+e]) -> no w_lds round-trip. t' staged in LDS once per block.
// adj + whbt tile register-prefetched one iter ahead; 1 barrier/iter (bt dbuf).
__global__ __launch_bounds__(512, 4) void k3_attn(
    const int* __restrict__ adj, const unsigned short* __restrict__ whbt,
    const float* __restrict__ s_in, const float* __restrict__ t_in,
    const unsigned* __restrict__ Tkey,
    unsigned short* __restrict__ num_bf, float* __restrict__ num_f32,
    float* __restrict__ den_out, int slice_mode)
{
    __shared__ unsigned short bt[2][128][72];
    __shared__ float tl[1024];
    const int t = threadIdx.x, lane = t & 63, wave = t >> 6;
    const int jc = blockIdx.x & 7, it = blockIdx.x >> 3;
    const int i0 = it * 128, jbase = jc * 1024;

    tl[t] = t_in[jbase + t];
    tl[t + 512] = t_in[jbase + t + 512];

    const int arow = lane & 15, g = lane >> 4;
    const int grow = i0 + wave * 16 + arow;
    const float sA = s_in[grow];
    const float Tv = key2f(Tkey[0]);
    const float zT = sA + Tv;
    const float mA = fmaxf(zT, 0.2f * zT);
    const int* adjrow = adj + (size_t)grow * N;
    const int srow = t >> 2, scol = (t & 3) * 16;
    const unsigned short* sbase = whbt + (size_t)srow * N + jbase + scol;

    f32x4 acc[8];
    const f32x4 zz = {0.f, 0.f, 0.f, 0.f};
    #pragma unroll
    for (int c = 0; c < 8; ++c) acc[c] = zz;
    float den = 0.f;

    // prologue: stage bt tile 0, prefetch adj for jt=0
    short8 sr0 = *(const short8*)sbase;
    short8 sr1 = *(const short8*)(sbase + 8);
    int4 av0 = *(const int4*)(adjrow + jbase + g * 8);
    int4 av1 = *(const int4*)(adjrow + jbase + g * 8 + 4);
    int4 av2 = *(const int4*)(adjrow + jbase + 32 + g * 8);
    int4 av3 = *(const int4*)(adjrow + jbase + 32 + g * 8 + 4);
    *(short8*)&bt[0][srow][scol]     = sr0;
    *(short8*)&bt[0][srow][scol + 8] = sr1;
    __syncthreads();

    #pragma unroll 1
    for (int jt = 0; jt < 16; ++jt) {
        const int cur = jt & 1, jl = jt * 64;
        // t' from LDS (lgkm only, off the vmcnt path)
        float4 ta = *(const float4*)&tl[jl + g * 8];
        float4 tb = *(const float4*)&tl[jl + g * 8 + 4];
        float4 tc = *(const float4*)&tl[jl + 32 + g * 8];
        float4 td = *(const float4*)&tl[jl + 32 + g * 8 + 4];
        // prefetch next adj + next bt tile into regs
        int4 an0, an1, an2, an3; short8 n0, n1;
        if (jt < 15) {
            const int* ap = adjrow + jbase + jl + 64;
            an0 = *(const int4*)(ap + g * 8);
            an1 = *(const int4*)(ap + g * 8 + 4);
            an2 = *(const int4*)(ap + 32 + g * 8);
            an3 = *(const int4*)(ap + 32 + g * 8 + 4);
            const unsigned short* p = sbase + (jt + 1) * 64;
            n0 = *(const short8*)p;
            n1 = *(const short8*)(p + 8);
        }
        // phase A: 16 w's straight into A-fragments (no memory wait: av in regs)
        float w[16];
        cw(&w[0],  av0, ta, sA, mA);
        cw(&w[4],  av1, tb, sA, mA);
        cw(&w[8],  av2, tc, sA, mA);
        cw(&w[12], av3, td, sA, mA);
        #pragma unroll
        for (int e = 0; e < 16; ++e) den += w[e];
        short8 af0, af1;
        #pragma unroll
        for (int e = 0; e < 8; ++e) {
            af0[e] = (short)f2b(w[e]);
            af1[e] = (short)f2b(w[8 + e]);
        }
        // phase B: 16 MFMA, B from LDS
        #pragma unroll
        for (int c = 0; c < 8; ++c) {
            short8 bf = *(const short8*)&bt[cur][c * 16 + arow][g * 8];
            acc[c] = __builtin_amdgcn_mfma_f32_16x16x32_bf16(af0, bf, acc[c], 0, 0, 0);
        }
        #pragma unroll
        for (int c = 0; c < 8; ++c) {
            short8 bf = *(const short8*)&bt[cur][c * 16 + arow][32 + g * 8];
            acc[c] = __builtin_amdgcn_mfma_f32_16x16x32_bf16(af1, bf, acc[c], 0, 0, 0);
        }
        // stage next tile (vmcnt drain lands here, after compute)
        if (jt < 15) {
            *(short8*)&bt[cur ^ 1][srow][scol]     = n0;
            *(short8*)&bt[cur ^ 1][srow][scol + 8] = n1;
            av0 = an0; av1 = an1; av2 = an2; av3 = an3;
            __syncthreads();
        }
    }

    // den: sum the 4 g-copies per row
    den += __shfl_xor(den, 16, 64);
    den += __shfl_xor(den, 32, 64);
    if (g == 0) atomicAdd(&den_out[grow], den);

    // num partials
    const int orow0 = i0 + wave * 16;
    if (slice_mode) {
        unsigned short* dst = num_bf + (size_t)jc * ((size_t)N * FOUT);
        #pragma unroll
        for (int c = 0; c < 8; ++c)
            #pragma unroll
            for (int q = 0; q < 4; ++q)
                dst[(size_t)(orow0 + g * 4 + q) * FOUT + c * 16 + arow] = f2b(acc[c][q]);
    } else {
        #pragma unroll
        for (int c = 0; c < 8; ++c)
            #pragma unroll
            for (int q = 0; q < 4; ++q)
                atomicAdd(&num_f32[(size_t)(orow0 + g * 4 + q) * FOUT + c * 16 + arow], acc[c][q]);
    }
}

// Kernel 4: reduce j-chunk partials, normalize, project, logmap0, elu + a*cos.
__global__ __launch_bounds__(256) void k4_epi(
    const unsigned short* __restrict__ numb, const float* __restrict__ numf,
    const float* __restrict__ den, float* __restrict__ out, int bfmode)
{
    const int row = blockIdx.x * 16 + (threadIdx.x >> 4);
    const int l = threadIdx.x & 15;
    const float inv = 1.0f / den[row];
    float v[8]; float ss = 0.f;
    #pragma unroll
    for (int c = 0; c < 8; ++c) {
        float x = 0.f;
        if (bfmode) {
            for (int s5 = 0; s5 < 8; ++s5) {
                unsigned b = numb[(size_t)s5 * N * FOUT + (size_t)row * FOUT + c * 16 + l];
                x += __uint_as_float(b << 16);
            }
        } else {
            x = numf[(size_t)row * FOUT + c * 16 + l];
        }
        v[c] = x * inv;
        ss += v[c] * v[c];
    }
    #pragma unroll
    for (int m = 1; m < 16; m <<= 1) ss += __shfl_xor(ss, m, 16);
    float nrm = sqrtf(ss);
    const float maxn = 1.0f - EPS_BALL;
    float scale1 = nrm > maxn ? maxn / nrm : 1.0f;
    float pn = fminf(nrm, maxn);
    float fac;
    if (pn < 1e-6f) fac = scale1;   // artanh(x)/x -> 1
    else fac = scale1 * (0.5f * __logf((1.f + pn) / (1.f - pn))) / pn;
    #pragma unroll
    for (int c = 0; c < 8; ++c) {
        float hv = v[c] * fac;
        float eluv = hv > 0.f ? hv : __expf(hv) - 1.f;
        out[(size_t)row * FOUT + c * 16 + l] = eluv + A_PARA * __cosf(hv + PHI);
    }
}

extern "C" void kernel_launch(void* const* d_in, const int* in_sizes, int n_in,
                              void* d_out, int out_size, void* d_ws, size_t ws_size,
                              hipStream_t stream) {
    const float* h   = (const float*)d_in[0];
    const int*   adj = (const int*)d_in[1];
    const float* W   = (const float*)d_in[2];
    const float* a   = (const float*)d_in[3];
    float* out = (float*)d_out;

    char* ws = (char*)d_ws;
    unsigned short* whbt = (unsigned short*)ws;                 // 2 MB bf16 Wh^T
    size_t off = (size_t)N * FOUT * 2;
    unsigned short* Wt = (unsigned short*)(ws + off); off += (size_t)FOUT * FIN * 2;  // 128 KB
    float* s  = (float*)(ws + off); off += (size_t)N * 4;
    float* tt = (float*)(ws + off); off += (size_t)N * 4;
    unsigned* Tkey = (unsigned*)(ws + off); off += 256;
    float* denb = (float*)(ws + off); off += (size_t)N * 4;
    const size_t slice_bytes = (size_t)N * FOUT * 2;            // bf16 slices, 2 MB each
    const bool fast = ws_size >= off + 8 * slice_bytes;
    unsigned short* numb = fast ? (unsigned short*)(ws + off) : nullptr;

    hipMemsetAsync(Tkey, 0, 4, stream);
    hipMemsetAsync(denb, 0, (size_t)N * 4, stream);
    if (!fast) hipMemsetAsync(out, 0, (size_t)N * FOUT * 4, stream);

    k0_wt<<<64, 256, 0, stream>>>(W, Wt);
    k1_gemm<<<N / 32, 256, 0, stream>>>(h, Wt, a, whbt, s, tt, Tkey);
    k3_attn<<<512, 512, 0, stream>>>(adj, whbt, s, tt, Tkey, numb, out, denb, fast ? 1 : 0);
    k4_epi<<<N / 16, 256, 0, stream>>>(numb, out, denb, out, fast ? 1 : 0);
}